// Round 1
// baseline (564.736 us; speedup 1.0000x reference)
//
#include <hip/hip_runtime.h>
#include <math.h>

#define Bz 4
#define Tz 2048
#define Cz 1024
#define Hz 16
#define Dz 64
#define MTOK (Bz*Tz)   // 8192

typedef __attribute__((ext_vector_type(8))) short short8;
typedef __attribute__((ext_vector_type(4))) short short4v;
typedef __attribute__((ext_vector_type(4))) float f32x4;

typedef unsigned int u32_g __attribute__((address_space(1)));
typedef unsigned int u32_l __attribute__((address_space(3)));

__device__ __forceinline__ unsigned short f2bf(float f) {
    unsigned int u = __float_as_uint(f);
    u += 0x7fffu + ((u >> 16) & 1u);
    return (unsigned short)(u >> 16);
}
__device__ __forceinline__ float bf2f(unsigned short h) {
    return __uint_as_float((unsigned int)h << 16);
}

__device__ __forceinline__ void async_cp16(const unsigned short* g, unsigned short* l) {
    __builtin_amdgcn_global_load_lds((const u32_g*)g, (u32_l*)l, 16, 0, 0);
}

#define BARX() __builtin_amdgcn_s_barrier()
#define LGKM0() do { asm volatile("s_waitcnt lgkmcnt(0)" ::: "memory"); __builtin_amdgcn_sched_barrier(0); } while (0)
#define VMC(n) asm volatile("s_waitcnt vmcnt(" #n ")" ::: "memory")

// ---------------- weight transpose: W[K][N] f32 -> Wt[N][K] bf16 ----------------
__global__ void transpose_w(const float* __restrict__ W, unsigned short* __restrict__ Wt,
                            int K, int N) {
    __shared__ float tile[32][33];
    int n0 = blockIdx.x * 32, k0 = blockIdx.y * 32;
    int tx = threadIdx.x, ty = threadIdx.y;   // (32, 8)
    #pragma unroll
    for (int i = 0; i < 4; i++)
        tile[ty + i * 8][tx] = W[(size_t)(k0 + ty + i * 8) * N + n0 + tx];
    __syncthreads();
    #pragma unroll
    for (int i = 0; i < 4; i++)
        Wt[(size_t)(n0 + ty + i * 8) * K + k0 + tx] = f2bf(tile[tx][ty + i * 8]);
}

// ---------------- layernorm: fp32 in -> bf16 out ----------------
__global__ void ln_kernel(const float* __restrict__ x, const float* __restrict__ g,
                          const float* __restrict__ bb, unsigned short* __restrict__ out) {
    int tok = blockIdx.x, tid = threadIdx.x;
    const float4 v = ((const float4*)(x + (size_t)tok * Cz))[tid];
    float s = v.x + v.y + v.z + v.w;
    float sq = v.x * v.x + v.y * v.y + v.z * v.z + v.w * v.w;
    #pragma unroll
    for (int m = 1; m < 64; m <<= 1) { s += __shfl_xor(s, m); sq += __shfl_xor(sq, m); }
    __shared__ float red[8];
    int lane = tid & 63, wid = tid >> 6;
    if (!lane) { red[wid] = s; red[4 + wid] = sq; }
    __syncthreads();
    s = red[0] + red[1] + red[2] + red[3];
    sq = red[4] + red[5] + red[6] + red[7];
    float mu = s * (1.0f / Cz);
    float var = sq * (1.0f / Cz) - mu * mu;
    float rs = rsqrtf(var + 1e-5f);
    float4 gv = ((const float4*)g)[tid];
    float4 bv = ((const float4*)bb)[tid];
    short4v o;
    o[0] = f2bf((v.x - mu) * rs * gv.x + bv.x);
    o[1] = f2bf((v.y - mu) * rs * gv.y + bv.y);
    o[2] = f2bf((v.z - mu) * rs * gv.z + bv.z);
    o[3] = f2bf((v.w - mu) * rs * gv.w + bv.w);
    *(short4v*)(out + (size_t)tok * Cz + tid * 4) = o;
}

#define MODE_QKV 0
#define MODE_RESID 1
#define MODE_GELU 2

template <int MODE>
__device__ __forceinline__ void write_elem(int row, int col, float val, int N,
                                           float* __restrict__ outf, unsigned short* __restrict__ outb,
                                           const float* __restrict__ resid,
                                           unsigned short* __restrict__ qo, unsigned short* __restrict__ ko,
                                           unsigned short* __restrict__ vo) {
    if constexpr (MODE == MODE_QKV) {
        int which = col >> 10, cc = col & 1023;
        int hh = cc >> 6, dd = cc & 63;
        int b_ = row >> 11, t = row & 2047;
        if (which == 2) {
            vo[((size_t)(b_ * Hz + hh) * Dz + dd) * Tz + t] = f2bf(val);
        } else {
            unsigned short* dst = which ? ko : qo;
            dst[((size_t)(b_ * Hz + hh) * Tz + t) * Dz + dd] = f2bf(val);
        }
    } else if constexpr (MODE == MODE_RESID) {
        size_t idx = (size_t)row * N + col;
        outf[idx] = val + resid[idx];
    } else {  // MODE_GELU, tanh-form
        float c = val * (1.0f + 0.044715f * val * val);
        float e = __expf(1.5957691216057308f * c);
        outb[(size_t)row * N + col] = f2bf(val * e / (1.0f + e));
    }
}

// ================= 8-phase pipelined GEMM, BM=256 x BN=256, BK=64 ================
// C = A[M,K] @ Bt[N,K]^T. 512 threads = 8 waves (2M x 4N), per-wave 128x64.
// LDS: per operand 2 bufs x 2 K-slots(32) x 256 rows, 128 KiB total.
// Swizzle: physical 16B-seg p of row r holds logical seg p ^ ((r>>1)&3);
// staging pre-swizzles the GLOBAL source col, LDS dest stays linear (rule #21).
// Counted vmcnt: steady-state 8 loads (4 slots) in flight; never drained to 0
// except in the 2-tile epilogue. Slot liveness: a slot staged in phase q was
// last read >=1 barrier earlier (proof in session notes).
template <int MODE>
__launch_bounds__(512, 1)
__global__ void gemm8_n256(const unsigned short* __restrict__ A, const unsigned short* __restrict__ Bt,
                           int lda, int K, int N, const float* __restrict__ bias,
                           float* __restrict__ outf, unsigned short* __restrict__ outb,
                           const float* __restrict__ resid,
                           unsigned short* __restrict__ qo, unsigned short* __restrict__ ko,
                           unsigned short* __restrict__ vo) {
    __shared__ __align__(16) unsigned short As[2][2][256 * 32];   // 64 KiB
    __shared__ __align__(16) unsigned short Bs[2][2][256 * 32];   // 64 KiB
    const int tid = threadIdx.x;
    const int lane = tid & 63;
    const int wid = tid >> 6;
    const int quad = lane >> 4, l15 = lane & 15;
    const int gm = wid >> 2, gn = wid & 3;
    const int id = blockIdx.x;
    const int rr = id >> 3;
    const int m0 = ((id & 7) * 4 + (rr & 3)) * 256;   // XCD owns 4 contiguous m-tiles
    const int n0 = (rr >> 2) * 256;
    const int NT = K >> 6;

    // staging source: thread covers row (i*128 + tid/4), physical seg tid&3
    const int srow = tid >> 2;                       // 0..127
    const int lseg = (tid & 3) ^ ((tid >> 3) & 3);   // logical seg for this phys slot
    const unsigned short* Ag0 = A + (size_t)(m0 + srow) * lda + lseg * 8;
    const unsigned short* Ag1 = A + (size_t)(m0 + 128 + srow) * lda + lseg * 8;
    const unsigned short* Bg0 = Bt + (size_t)(n0 + srow) * lda + lseg * 8;
    const unsigned short* Bg1 = Bt + (size_t)(n0 + 128 + srow) * lda + lseg * 8;

    f32x4 acc[8][4] = {};
    short8 af[8], bf[4];

#define STA(bufd, kkd, tt) do { \
    async_cp16(Ag0 + (size_t)(tt) * 64 + (kkd) * 32, &As[bufd][kkd][tid * 8]); \
    async_cp16(Ag1 + (size_t)(tt) * 64 + (kkd) * 32, &As[bufd][kkd][4096 + tid * 8]); } while (0)
#define STB(bufd, kkd, tt) do { \
    async_cp16(Bg0 + (size_t)(tt) * 64 + (kkd) * 32, &Bs[bufd][kkd][tid * 8]); \
    async_cp16(Bg1 + (size_t)(tt) * 64 + (kkd) * 32, &Bs[bufd][kkd][4096 + tid * 8]); } while (0)
#define RDA(kkd) do { _Pragma("unroll") for (int mi = 0; mi < 8; mi++) { \
    const int ra = gm * 128 + mi * 16 + l15; \
    af[mi] = *(const short8*)&As[buf][kkd][ra * 32 + ((quad ^ ((ra >> 1) & 3)) << 3)]; } } while (0)
#define RDB2(kkd, nia, nib) do { \
    { const int rb = gn * 64 + (nia) * 16 + l15; \
      bf[nia] = *(const short8*)&Bs[buf][kkd][rb * 32 + ((quad ^ ((rb >> 1) & 3)) << 3)]; } \
    { const int rb = gn * 64 + (nib) * 16 + l15; \
      bf[nib] = *(const short8*)&Bs[buf][kkd][rb * 32 + ((quad ^ ((rb >> 1) & 3)) << 3)]; } } while (0)
#define MM2(nia, nib) do { _Pragma("unroll") for (int mi = 0; mi < 8; mi++) { \
    acc[mi][nia] = __builtin_amdgcn_mfma_f32_16x16x32_bf16(af[mi], bf[nia], acc[mi][nia], 0, 0, 0); \
    acc[mi][nib] = __builtin_amdgcn_mfma_f32_16x16x32_bf16(af[mi], bf[nib], acc[mi][nib], 0, 0, 0); } } while (0)

    // prologue: tile0 both slots + tile1 kk0 (12 loads); need first 4 landed
    STA(0, 0, 0); STB(0, 0, 0);
    STA(0, 1, 0); STB(0, 1, 0);
    STA(1, 0, 1); STB(1, 0, 1);
    VMC(8);
    BARX();

    for (int t = 0; t < NT; t++) {
        const int buf = t & 1;
        const int nb = buf ^ 1;
        // ---- P0: kk0, ni{0,1}; stage A_kk1[t+1] ----
        RDA(0); RDB2(0, 0, 1);
        if (t + 1 < NT) STA(nb, 1, t + 1);
        BARX(); LGKM0();
        __builtin_amdgcn_s_setprio(1);
        MM2(0, 1);
        __builtin_amdgcn_s_setprio(0);
        BARX();
        // ---- P1: kk0, ni{2,3}; stage B_kk1[t+1] ----
        RDB2(0, 2, 3);
        if (t + 1 < NT) STB(nb, 1, t + 1);
        BARX(); LGKM0();
        __builtin_amdgcn_s_setprio(1);
        MM2(2, 3);
        __builtin_amdgcn_s_setprio(0);
        if (t + 1 < NT) { VMC(8); } else { VMC(0); }   // kk1[t] landed before P2 reads
        BARX();
        // ---- P2: kk1, ni{0,1}; stage A_kk0[t+2] (slot freed after P0) ----
        RDA(1); RDB2(1, 0, 1);
        if (t + 2 < NT) STA(buf, 0, t + 2);
        BARX(); LGKM0();
        __builtin_amdgcn_s_setprio(1);
        MM2(0, 1);
        __builtin_amdgcn_s_setprio(0);
        BARX();
        // ---- P3: kk1, ni{2,3}; stage B_kk0[t+2] (slot freed after P1) ----
        RDB2(1, 2, 3);
        if (t + 2 < NT) STB(buf, 0, t + 2);
        BARX(); LGKM0();
        __builtin_amdgcn_s_setprio(1);
        MM2(2, 3);
        __builtin_amdgcn_s_setprio(0);
        if (t + 2 < NT) { VMC(8); } else if (t + 1 < NT) { VMC(4); } else { VMC(0); }
        BARX();
    }
#undef STA
#undef STB
#undef RDA
#undef RDB2
#undef MM2

    #pragma unroll
    for (int ni = 0; ni < 4; ni++) {
        const int col = n0 + gn * 64 + ni * 16 + l15;
        const float bv = bias[col];
        #pragma unroll
        for (int mi = 0; mi < 8; mi++) {
            #pragma unroll
            for (int r = 0; r < 4; r++) {
                const int row = m0 + gm * 128 + mi * 16 + quad * 4 + r;
                write_elem<MODE>(row, col, acc[mi][ni][r] + bv, N, outf, outb, resid, qo, ko, vo);
            }
        }
    }
}

// ================= pipelined GEMM, BM=256 x BN=128, BK=64 (N=1024 GEMMs) =========
// 512 threads = 8 waves (4M x 2N), per-wave 64x64. 2 phases/tile (one per K-slot).
// Grid = 32 x 8 = 256 blocks -> exactly 1/CU (vs 128 at BN=256).
template <int MODE>
__launch_bounds__(512, 1)
__global__ void gemm8_n128(const unsigned short* __restrict__ A, const unsigned short* __restrict__ Bt,
                           int lda, int K, int N, const float* __restrict__ bias,
                           float* __restrict__ outf, unsigned short* __restrict__ outb,
                           const float* __restrict__ resid,
                           unsigned short* __restrict__ qo, unsigned short* __restrict__ ko,
                           unsigned short* __restrict__ vo) {
    __shared__ __align__(16) unsigned short As[2][2][256 * 32];   // 64 KiB
    __shared__ __align__(16) unsigned short Bs[2][2][128 * 32];   // 32 KiB
    const int tid = threadIdx.x;
    const int lane = tid & 63;
    const int wid = tid >> 6;
    const int quad = lane >> 4, l15 = lane & 15;
    const int gm = wid >> 1, gn = wid & 1;
    const int id = blockIdx.x;
    const int rr = id >> 3;
    const int m0 = ((id & 7) * 4 + (rr & 3)) * 256;
    const int n0 = (rr >> 2) * 128;
    const int NT = K >> 6;

    const int srow = tid >> 2;
    const int lseg = (tid & 3) ^ ((tid >> 3) & 3);
    const unsigned short* Ag0 = A + (size_t)(m0 + srow) * lda + lseg * 8;
    const unsigned short* Ag1 = A + (size_t)(m0 + 128 + srow) * lda + lseg * 8;
    const unsigned short* Bg0 = Bt + (size_t)(n0 + srow) * lda + lseg * 8;

    f32x4 acc[4][4] = {};
    short8 af[4], bf[4];

#define STA(bufd, kkd, tt) do { \
    async_cp16(Ag0 + (size_t)(tt) * 64 + (kkd) * 32, &As[bufd][kkd][tid * 8]); \
    async_cp16(Ag1 + (size_t)(tt) * 64 + (kkd) * 32, &As[bufd][kkd][4096 + tid * 8]); } while (0)
#define STB(bufd, kkd, tt) \
    async_cp16(Bg0 + (size_t)(tt) * 64 + (kkd) * 32, &Bs[bufd][kkd][tid * 8])
#define RDA(kkd) do { _Pragma("unroll") for (int mi = 0; mi < 4; mi++) { \
    const int ra = gm * 64 + mi * 16 + l15; \
    af[mi] = *(const short8*)&As[buf][kkd][ra * 32 + ((quad ^ ((ra >> 1) & 3)) << 3)]; } } while (0)
#define RDB(kkd) do { _Pragma("unroll") for (int ni = 0; ni < 4; ni++) { \
    const int rb = gn * 64 + ni * 16 + l15; \
    bf[ni] = *(const short8*)&Bs[buf][kkd][rb * 32 + ((quad ^ ((rb >> 1) & 3)) << 3)]; } } while (0)
#define MM16() do { _Pragma("unroll") for (int mi = 0; mi < 4; mi++) \
    _Pragma("unroll") for (int ni = 0; ni < 4; ni++) \
        acc[mi][ni] = __builtin_amdgcn_mfma_f32_16x16x32_bf16(af[mi], bf[ni], acc[mi][ni], 0, 0, 0); } while (0)

    // prologue: t0 kk0 (3), t0 kk1 (3), t1 kk0 (3); need first 3 landed
    STA(0, 0, 0); STB(0, 0, 0);
    STA(0, 1, 0); STB(0, 1, 0);
    STA(1, 0, 1); STB(1, 0, 1);
    VMC(6);
    BARX();

    for (int t = 0; t < NT; t++) {
        const int buf = t & 1;
        const int nb = buf ^ 1;
        // ---- P0: kk0; stage kk1[t+1] ----
        RDA(0); RDB(0);
        if (t + 1 < NT) { STA(nb, 1, t + 1); STB(nb, 1, t + 1); }
        BARX(); LGKM0();
        __builtin_amdgcn_s_setprio(1);
        MM16();
        __builtin_amdgcn_s_setprio(0);
        if (t + 1 < NT) { VMC(6); } else { VMC(0); }
        BARX();
        // ---- P1: kk1; stage kk0[t+2] (slots freed after P0) ----
        RDA(1); RDB(1);
        if (t + 2 < NT) { STA(buf, 0, t + 2); STB(buf, 0, t + 2); }
        BARX(); LGKM0();
        __builtin_amdgcn_s_setprio(1);
        MM16();
        __builtin_amdgcn_s_setprio(0);
        if (t + 2 < NT) { VMC(6); } else if (t + 1 < NT) { VMC(3); } else { VMC(0); }
        BARX();
    }
#undef STA
#undef STB
#undef RDA
#undef RDB
#undef MM16

    #pragma unroll
    for (int ni = 0; ni < 4; ni++) {
        const int col = n0 + gn * 64 + ni * 16 + l15;
        const float bv = bias[col];
        #pragma unroll
        for (int mi = 0; mi < 4; mi++) {
            #pragma unroll
            for (int r = 0; r < 4; r++) {
                const int row = m0 + gm * 64 + mi * 16 + quad * 4 + r;
                write_elem<MODE>(row, col, acc[mi][ni][r] + bv, N, outf, outb, resid, qo, ko, vo);
            }
        }
    }
}

// ---------------- causal flash attention, bf16 MFMA (unchanged this round) ------
#define ATT_SC 0.18033688011112042f   // 0.125 * log2(e)
__launch_bounds__(256)
__global__ void attn_kernel(const unsigned short* __restrict__ qb, const unsigned short* __restrict__ kb,
                            const unsigned short* __restrict__ vt, unsigned short* __restrict__ y) {
    __shared__ __align__(16) unsigned short Klds[64 * 64];
    __shared__ __align__(16) unsigned short Vtl[64 * 64];
    __shared__ __align__(16) unsigned short Plds[4][16 * 72];
    const int tid = threadIdx.x;
    const int lane = tid & 63, wid = tid >> 6;
    const int quad = lane >> 4, l15 = lane & 15;
    const int bh = blockIdx.x & 63;
    const int qt = 15 - (int)(blockIdx.x >> 6);
    const size_t baseT = (size_t)bh * Tz;
    const size_t vbase = (size_t)bh * Dz;
    const int qb0 = qt * 128;

    short8 qf[2][2];
    {
        const unsigned short* q0p = qb + (baseT + qb0 + wid * 16 + l15) * Dz + quad * 8;
        qf[0][0] = *(const short8*)q0p;
        qf[0][1] = *(const short8*)(q0p + 32);
        const unsigned short* q1p = q0p + (size_t)64 * Dz;
        qf[1][0] = *(const short8*)q1p;
        qf[1][1] = *(const short8*)(q1p + 32);
    }

    f32x4 o[2][4] = {};
    float lsum[2][4] = {{0.f,0.f,0.f,0.f},{0.f,0.f,0.f,0.f}};

    const int srow = lane >> 3;
    const int swz = ((lane & 7) ^ srow) * 8;
    const unsigned short* kg0 = kb + (baseT + wid * 8 + srow) * Dz + swz;
    const unsigned short* kg1 = kg0 + (size_t)32 * Dz;
    const unsigned short* vg0 = vt + (vbase + wid * 8 + srow) * Tz + swz;
    const unsigned short* vg1 = vg0 + (size_t)32 * Tz;
    unsigned short* kl0 = &Klds[wid * 512 + lane * 8];
    unsigned short* kl1 = kl0 + 2048;
    unsigned short* vl0 = &Vtl[wid * 512 + lane * 8];
    unsigned short* vl1 = vl0 + 2048;

    const int nchunk = 2 * qt + 2;

    for (int ci = 0; ci < nchunk; ci++) {
        const int k0 = ci * 64;
        async_cp16(kg0 + (size_t)k0 * Dz, kl0);
        async_cp16(kg1 + (size_t)k0 * Dz, kl1);
        async_cp16(vg0 + k0, vl0);
        async_cp16(vg1 + k0, vl1);
        __syncthreads();

        #pragma unroll
        for (int t = 0; t < 2; t++) {
            if (t == 0 && ci == nchunk - 1) continue;
            const bool diag = (ci == nchunk - 2 + t);

            f32x4 s[4];
            #pragma unroll
            for (int c = 0; c < 4; c++) {
                const int rk = c * 16 + l15;
                short8 kf0 = *(const short8*)&Klds[rk * 64 + ((quad ^ (rk & 7)) * 8)];
                short8 kf1 = *(const short8*)&Klds[rk * 64 + (((quad + 4) ^ (rk & 7)) * 8)];
                f32x4 z = {};
                z = __builtin_amdgcn_mfma_f32_16x16x32_bf16(qf[t][0], kf0, z, 0, 0, 0);
                s[c] = __builtin_amdgcn_mfma_f32_16x16x32_bf16(qf[t][1], kf1, z, 0, 0, 0);
            }
            const int qr = qb0 + t * 64 + wid * 16 + quad * 4;
            #pragma unroll
            for (int c = 0; c < 4; c++)
                #pragma unroll
                for (int r = 0; r < 4; r++) {
                    float p = exp2f(s[c][r] * ATT_SC);
                    if (diag) {
                        int key = k0 + c * 16 + l15;
                        p = (key <= qr + r) ? p : 0.f;
                    }
                    s[c][r] = p;
                    lsum[t][r] += p;
                }
            unsigned short* P = Plds[wid];
            #pragma unroll
            for (int c = 0; c < 4; c++)
                #pragma unroll
                for (int r = 0; r < 4; r++)
                    P[(quad * 4 + r) * 72 + c * 16 + l15] = f2bf(s[c][r]);
            short8 pf0 = *(const short8*)&P[l15 * 72 + quad * 8];
            short8 pf1 = *(const short8*)&P[l15 * 72 + 32 + quad * 8];
            #pragma unroll
            for (int nc = 0; nc < 4; nc++) {
                const int rv = nc * 16 + l15;
                short8 vf0 = *(const short8*)&Vtl[rv * 64 + ((quad ^ (rv & 7)) * 8)];
                short8 vf1 = *(const short8*)&Vtl[rv * 64 + (((quad + 4) ^ (rv & 7)) * 8)];
                o[t][nc] = __builtin_amdgcn_mfma_f32_16x16x32_bf16(pf0, vf0, o[t][nc], 0, 0, 0);
                o[t][nc] = __builtin_amdgcn_mfma_f32_16x16x32_bf16(pf1, vf1, o[t][nc], 0, 0, 0);
            }
        }
        __syncthreads();
    }

    const int b_ = bh >> 4, hh = bh & 15;
    #pragma unroll
    for (int t = 0; t < 2; t++)
        #pragma unroll
        for (int r = 0; r < 4; r++) {
            float ls = lsum[t][r];
            #pragma unroll
            for (int m = 1; m < 16; m <<= 1) ls += __shfl_xor(ls, m);
            float inv = 1.0f / ls;
            size_t tok = (size_t)qb0 + t * 64 + wid * 16 + quad * 4 + r;
            unsigned short* yr = y + ((size_t)b_ * Tz + tok) * Cz + hh * Dz;
            #pragma unroll
            for (int nc = 0; nc < 4; nc++)
                yr[nc * 16 + l15] = f2bf(o[t][nc][r] * inv);
        }
}

extern "C" void kernel_launch(void* const* d_in, const int* in_sizes, int n_in,
                              void* d_out, int out_size, void* d_ws, size_t ws_size,
                              hipStream_t stream) {
    const float* x    = (const float*)d_in[0];
    const float* ln1g = (const float*)d_in[1];
    const float* ln1b = (const float*)d_in[2];
    const float* Wqkv = (const float*)d_in[3];
    const float* bqkv = (const float*)d_in[4];
    const float* Wo   = (const float*)d_in[5];
    const float* bo   = (const float*)d_in[6];
    const float* ln2g = (const float*)d_in[7];
    const float* ln2b = (const float*)d_in[8];
    const float* Wfc  = (const float*)d_in[9];
    const float* bfc  = (const float*)d_in[10];
    const float* Wpr  = (const float*)d_in[11];
    const float* bpr  = (const float*)d_in[12];
    float* out = (float*)d_out;

    char* ws = (char*)d_ws;
    size_t off = 0;
    auto alloc = [&](size_t bytes) { void* p = ws + off; off += (bytes + 255) & ~(size_t)255; return p; };
    unsigned short* wqkv_t = (unsigned short*)alloc((size_t)3072 * 1024 * 2);
    unsigned short* wo_t   = (unsigned short*)alloc((size_t)1024 * 1024 * 2);
    unsigned short* wfc_t  = (unsigned short*)alloc((size_t)4096 * 1024 * 2);
    unsigned short* wpr_t  = (unsigned short*)alloc((size_t)1024 * 4096 * 2);
    unsigned short* h1     = (unsigned short*)alloc((size_t)MTOK * Cz * 2);
    unsigned short* qbuf   = (unsigned short*)alloc((size_t)MTOK * Cz * 2);
    unsigned short* kbuf   = (unsigned short*)alloc((size_t)MTOK * Cz * 2);
    unsigned short* vbuf   = (unsigned short*)alloc((size_t)MTOK * Cz * 2);
    unsigned short* ybuf   = (unsigned short*)alloc((size_t)MTOK * Cz * 2);
    float*          x1     = (float*)alloc((size_t)MTOK * Cz * 4);
    unsigned short* h2     = (unsigned short*)alloc((size_t)MTOK * Cz * 2);
    unsigned short* fbuf   = (unsigned short*)alloc((size_t)MTOK * 4096 * 2);

    dim3 tb(32, 8);
    transpose_w<<<dim3(3072 / 32, 1024 / 32), tb, 0, stream>>>(Wqkv, wqkv_t, 1024, 3072);
    transpose_w<<<dim3(1024 / 32, 1024 / 32), tb, 0, stream>>>(Wo, wo_t, 1024, 1024);
    transpose_w<<<dim3(4096 / 32, 1024 / 32), tb, 0, stream>>>(Wfc, wfc_t, 1024, 4096);
    transpose_w<<<dim3(1024 / 32, 4096 / 32), tb, 0, stream>>>(Wpr, wpr_t, 4096, 1024);

    ln_kernel<<<MTOK, 256, 0, stream>>>(x, ln1g, ln1b, h1);
    // QKV: M=8192, K=1024, N=3072 -> 32 x 12 = 384 blocks
    gemm8_n256<MODE_QKV><<<384, 512, 0, stream>>>(h1, wqkv_t, 1024, 1024, 3072, bqkv,
                                                  nullptr, nullptr, nullptr, qbuf, kbuf, vbuf);
    attn_kernel<<<1024, 256, 0, stream>>>(qbuf, kbuf, vbuf, ybuf);
    // O-proj: N=1024 -> BN=128, 32 x 8 = 256 blocks
    gemm8_n128<MODE_RESID><<<256, 512, 0, stream>>>(ybuf, wo_t, 1024, 1024, 1024, bo,
                                                    x1, nullptr, x, nullptr, nullptr, nullptr);
    ln_kernel<<<MTOK, 256, 0, stream>>>(x1, ln2g, ln2b, h2);
    // FC: M=8192, K=1024, N=4096 -> 32 x 16 = 512 blocks
    gemm8_n256<MODE_GELU><<<512, 512, 0, stream>>>(h2, wfc_t, 1024, 1024, 4096, bfc,
                                                   nullptr, fbuf, nullptr, nullptr, nullptr, nullptr);
    // PR: M=8192, K=4096, N=1024 -> BN=128, 256 blocks
    gemm8_n128<MODE_RESID><<<256, 512, 0, stream>>>(fbuf, wpr_t, 4096, 4096, 1024, bpr,
                                                    out, nullptr, x1, nullptr, nullptr, nullptr);
}

// Round 2
// 555.585 us; speedup vs baseline: 1.0165x; 1.0165x over previous
//
#include <hip/hip_runtime.h>
#include <math.h>

#define Bz 4
#define Tz 2048
#define Cz 1024
#define Hz 16
#define Dz 64
#define MTOK (Bz*Tz)   // 8192

typedef __attribute__((ext_vector_type(8))) short short8;
typedef __attribute__((ext_vector_type(4))) short short4v;
typedef __attribute__((ext_vector_type(4))) float f32x4;

typedef unsigned int u32_g __attribute__((address_space(1)));
typedef unsigned int u32_l __attribute__((address_space(3)));

__device__ __forceinline__ unsigned short f2bf(float f) {
    unsigned int u = __float_as_uint(f);
    u += 0x7fffu + ((u >> 16) & 1u);
    return (unsigned short)(u >> 16);
}
__device__ __forceinline__ float bf2f(unsigned short h) {
    return __uint_as_float((unsigned int)h << 16);
}

__device__ __forceinline__ void async_cp16(const unsigned short* g, unsigned short* l) {
    __builtin_amdgcn_global_load_lds((const u32_g*)g, (u32_l*)l, 16, 0, 0);
}

#define BARX() __builtin_amdgcn_s_barrier()
#define VMC(n) asm volatile("s_waitcnt vmcnt(" #n ")" ::: )
// block DS ops from crossing (keeps ds_reads after the vmcnt guaranteeing their
// data landed); ALU/VALU/SALU/MFMA/VMEM may cross freely.
#define SCHEDF() __builtin_amdgcn_sched_barrier(0x7F)

// ---------------- weight transpose: W[K][N] f32 -> Wt[N][K] bf16 ----------------
__global__ void transpose_w(const float* __restrict__ W, unsigned short* __restrict__ Wt,
                            int K, int N) {
    __shared__ float tile[32][33];
    int n0 = blockIdx.x * 32, k0 = blockIdx.y * 32;
    int tx = threadIdx.x, ty = threadIdx.y;   // (32, 8)
    #pragma unroll
    for (int i = 0; i < 4; i++)
        tile[ty + i * 8][tx] = W[(size_t)(k0 + ty + i * 8) * N + n0 + tx];
    __syncthreads();
    #pragma unroll
    for (int i = 0; i < 4; i++)
        Wt[(size_t)(n0 + ty + i * 8) * K + k0 + tx] = f2bf(tile[tx][ty + i * 8]);
}

// ---------------- V transpose: vtmp[B*H][T][D] -> vt[B*H][D][T] -----------------
__global__ void transpose_v(const unsigned short* __restrict__ in, unsigned short* __restrict__ out) {
    __shared__ unsigned short tile[64][68];
    const int bh = blockIdx.x;        // 0..63
    const int t0 = blockIdx.y * 64;   // 32 tiles along T
    const int tid = threadIdx.x;      // 256
    const int r4 = tid >> 4;          // 0..15
    const int c4 = tid & 15;          // 0..15
    #pragma unroll
    for (int p = 0; p < 4; p++) {
        const int r = p * 16 + r4;
        *(short4v*)&tile[r][c4 * 4] =
            *(const short4v*)&in[((size_t)bh * Tz + t0 + r) * Dz + c4 * 4];
    }
    __syncthreads();
    #pragma unroll
    for (int p = 0; p < 4; p++) {
        const int d = p * 16 + r4;
        short4v o;
        #pragma unroll
        for (int j = 0; j < 4; j++) o[j] = tile[c4 * 4 + j][d];
        *(short4v*)&out[((size_t)bh * Dz + d) * Tz + t0 + c4 * 4] = o;
    }
}

// ---------------- layernorm: fp32 in -> bf16 out ----------------
__global__ void ln_kernel(const float* __restrict__ x, const float* __restrict__ g,
                          const float* __restrict__ bb, unsigned short* __restrict__ out) {
    int tok = blockIdx.x, tid = threadIdx.x;
    const float4 v = ((const float4*)(x + (size_t)tok * Cz))[tid];
    float s = v.x + v.y + v.z + v.w;
    float sq = v.x * v.x + v.y * v.y + v.z * v.z + v.w * v.w;
    #pragma unroll
    for (int m = 1; m < 64; m <<= 1) { s += __shfl_xor(s, m); sq += __shfl_xor(sq, m); }
    __shared__ float red[8];
    int lane = tid & 63, wid = tid >> 6;
    if (!lane) { red[wid] = s; red[4 + wid] = sq; }
    __syncthreads();
    s = red[0] + red[1] + red[2] + red[3];
    sq = red[4] + red[5] + red[6] + red[7];
    float mu = s * (1.0f / Cz);
    float var = sq * (1.0f / Cz) - mu * mu;
    float rs = rsqrtf(var + 1e-5f);
    float4 gv = ((const float4*)g)[tid];
    float4 bv = ((const float4*)bb)[tid];
    short4v o;
    o[0] = f2bf((v.x - mu) * rs * gv.x + bv.x);
    o[1] = f2bf((v.y - mu) * rs * gv.y + bv.y);
    o[2] = f2bf((v.z - mu) * rs * gv.z + bv.z);
    o[3] = f2bf((v.w - mu) * rs * gv.w + bv.w);
    *(short4v*)(out + (size_t)tok * Cz + tid * 4) = o;
}

#define MODE_QKV 0
#define MODE_RESID 1
#define MODE_GELU 2

template <int MODE>
__device__ __forceinline__ void write_elem(int row, int col, float val, int N,
                                           float* __restrict__ outf, unsigned short* __restrict__ outb,
                                           const float* __restrict__ resid,
                                           unsigned short* __restrict__ qo, unsigned short* __restrict__ ko,
                                           unsigned short* __restrict__ vo) {
    if constexpr (MODE == MODE_QKV) {
        int which = col >> 10, cc = col & 1023;
        int hh = cc >> 6, dd = cc & 63;
        int b_ = row >> 11, t = row & 2047;
        unsigned short* dst = (which == 0) ? qo : (which == 1) ? ko : vo;
        dst[((size_t)(b_ * Hz + hh) * Tz + t) * Dz + dd] = f2bf(val);
    } else if constexpr (MODE == MODE_RESID) {
        size_t idx = (size_t)row * N + col;
        outf[idx] = val + resid[idx];
    } else {  // MODE_GELU, tanh-form
        float c = val * (1.0f + 0.044715f * val * val);
        float e = __expf(1.5957691216057308f * c);
        outb[(size_t)row * N + col] = f2bf(val * e / (1.0f + e));
    }
}

// ================= pipelined GEMM, BM=256 x BN=256, BK=64 ================
// 512 threads = 8 waves (2M x 4N), per-wave 128x64. LDS 128 KiB (2 dbuf x 2 kslot).
// 4 phases/K-tile, balanced ds_reads (8,4,8,4) with B-frag reuse; one 16 KB stage
// per phase; counted vmcnt(4) only at half-tile boundaries; raw s_barrier;
// NO lgkmcnt(0)/sched_barrier(0) fences (compiler inserts fine-grained lgkm).
template <int MODE>
__launch_bounds__(512, 1)
__global__ void gemm8_n256(const unsigned short* __restrict__ A, const unsigned short* __restrict__ Bt,
                           int lda, int K, int N, const float* __restrict__ bias,
                           float* __restrict__ outf, unsigned short* __restrict__ outb,
                           const float* __restrict__ resid,
                           unsigned short* __restrict__ qo, unsigned short* __restrict__ ko,
                           unsigned short* __restrict__ vo) {
    __shared__ __align__(16) unsigned short As[2][2][256 * 32];   // 64 KiB
    __shared__ __align__(16) unsigned short Bs[2][2][256 * 32];   // 64 KiB
    const int tid = threadIdx.x;
    const int lane = tid & 63;
    const int wid = tid >> 6;
    const int quad = lane >> 4, l15 = lane & 15;
    const int gm = wid >> 2, gn = wid & 3;
    const int id = blockIdx.x;
    const int rr = id >> 3;
    const int m0 = ((id & 7) * 4 + (rr & 3)) * 256;   // XCD owns 4 contiguous m-tiles
    const int n0 = (rr >> 2) * 256;
    const int NT = K >> 6;

    // staging: thread -> row tid/4 (and +128), physical 16B-seg tid&3,
    // global col pre-swizzled so LDS dest stays linear (both-sides swizzle).
    const int lseg = (tid & 3) ^ ((tid >> 3) & 3);
    const int srow = tid >> 2;
    const unsigned short* Ag0 = A + (size_t)(m0 + srow) * lda + lseg * 8;
    const unsigned short* Ag1 = A + (size_t)(m0 + 128 + srow) * lda + lseg * 8;
    const unsigned short* Bg0 = Bt + (size_t)(n0 + srow) * lda + lseg * 8;
    const unsigned short* Bg1 = Bt + (size_t)(n0 + 128 + srow) * lda + lseg * 8;

    f32x4 acc[8][4] = {};
    short8 af[4], bf[4];

#define STA(bufd, kkd, tt) do { \
    async_cp16(Ag0 + (size_t)(tt) * 64 + (kkd) * 32, &As[bufd][kkd][tid * 8]); \
    async_cp16(Ag1 + (size_t)(tt) * 64 + (kkd) * 32, &As[bufd][kkd][4096 + tid * 8]); } while (0)
#define STB(bufd, kkd, tt) do { \
    async_cp16(Bg0 + (size_t)(tt) * 64 + (kkd) * 32, &Bs[bufd][kkd][tid * 8]); \
    async_cp16(Bg1 + (size_t)(tt) * 64 + (kkd) * 32, &Bs[bufd][kkd][4096 + tid * 8]); } while (0)
#define RDA4(kkd, mb) do { _Pragma("unroll") for (int j = 0; j < 4; j++) { \
    const int ra = gm * 128 + ((mb) + j) * 16 + l15; \
    af[j] = *(const short8*)&As[buf][kkd][ra * 32 + ((quad ^ ((ra >> 1) & 3)) << 3)]; } } while (0)
#define RDB4(kkd) do { _Pragma("unroll") for (int j = 0; j < 4; j++) { \
    const int rb = gn * 64 + j * 16 + l15; \
    bf[j] = *(const short8*)&Bs[buf][kkd][rb * 32 + ((quad ^ ((rb >> 1) & 3)) << 3)]; } } while (0)
#define MFMA16(mb) do { _Pragma("unroll") for (int j = 0; j < 4; j++) \
    _Pragma("unroll") for (int ni = 0; ni < 4; ni++) \
        acc[(mb) + j][ni] = __builtin_amdgcn_mfma_f32_16x16x32_bf16(af[j], bf[ni], acc[(mb) + j][ni], 0, 0, 0); } while (0)

    // prologue: tile0 fully staged; ks0 must be landed (4 newest may fly)
    STA(0, 0, 0); STB(0, 0, 0);
    STA(0, 1, 0); STB(0, 1, 0);
    VMC(4);
    SCHEDF();
    BARX();

    for (int t = 0; t < NT - 1; t++) {
        const int buf = t & 1;
        const int nb = buf ^ 1;
        // ---- A: ks0, mi 0-3 (8 reads); stage A-ks0[t+1] ----
        RDA4(0, 0); RDB4(0);
        STA(nb, 0, t + 1);
        BARX();
        __builtin_amdgcn_s_setprio(1);
        MFMA16(0);
        __builtin_amdgcn_s_setprio(0);
        BARX();
        // ---- B: ks0, mi 4-7 (4 reads, bf reuse); stage B-ks0[t+1] ----
        RDA4(0, 4);
        STB(nb, 0, t + 1);
        BARX();
        __builtin_amdgcn_s_setprio(1);
        MFMA16(4);
        __builtin_amdgcn_s_setprio(0);
        VMC(4);      // ks1[t] (oldest 4) landed; ks0[t+1] (newest 4) may fly
        SCHEDF();
        BARX();
        // ---- C: ks1, mi 0-3; stage A-ks1[t+1] ----
        RDA4(1, 0); RDB4(1);
        STA(nb, 1, t + 1);
        BARX();
        __builtin_amdgcn_s_setprio(1);
        MFMA16(0);
        __builtin_amdgcn_s_setprio(0);
        BARX();
        // ---- D: ks1, mi 4-7; stage B-ks1[t+1] ----
        RDA4(1, 4);
        STB(nb, 1, t + 1);
        BARX();
        __builtin_amdgcn_s_setprio(1);
        MFMA16(4);
        __builtin_amdgcn_s_setprio(0);
        VMC(4);      // ks0[t+1] landed; ks1[t+1] may fly
        SCHEDF();
        BARX();
    }
    {   // tail tile: no stages; drain what remains
        const int buf = (NT - 1) & 1;
        RDA4(0, 0); RDB4(0);
        BARX();
        __builtin_amdgcn_s_setprio(1); MFMA16(0); __builtin_amdgcn_s_setprio(0);
        BARX();
        RDA4(0, 4);
        BARX();
        __builtin_amdgcn_s_setprio(1); MFMA16(4); __builtin_amdgcn_s_setprio(0);
        VMC(0);
        SCHEDF();
        BARX();
        RDA4(1, 0); RDB4(1);
        BARX();
        __builtin_amdgcn_s_setprio(1); MFMA16(0); __builtin_amdgcn_s_setprio(0);
        BARX();
        RDA4(1, 4);
        BARX();
        __builtin_amdgcn_s_setprio(1); MFMA16(4); __builtin_amdgcn_s_setprio(0);
    }
#undef STA
#undef STB
#undef RDA4
#undef RDB4
#undef MFMA16

    #pragma unroll
    for (int ni = 0; ni < 4; ni++) {
        const int col = n0 + gn * 64 + ni * 16 + l15;
        const float bv = bias[col];
        #pragma unroll
        for (int mi = 0; mi < 8; mi++) {
            #pragma unroll
            for (int r = 0; r < 4; r++) {
                const int row = m0 + gm * 128 + mi * 16 + quad * 4 + r;
                write_elem<MODE>(row, col, acc[mi][ni][r] + bv, N, outf, outb, resid, qo, ko, vo);
            }
        }
    }
}

// ================= pipelined GEMM, BM=256 x BN=128, BK=64 (N=1024) ==============
// 512 threads = 8 waves (4M x 2N), per-wave 64x64. 2 phases/K-tile. Grid 256 = 1/CU.
template <int MODE>
__launch_bounds__(512, 1)
__global__ void gemm8_n128(const unsigned short* __restrict__ A, const unsigned short* __restrict__ Bt,
                           int lda, int K, int N, const float* __restrict__ bias,
                           float* __restrict__ outf, unsigned short* __restrict__ outb,
                           const float* __restrict__ resid,
                           unsigned short* __restrict__ qo, unsigned short* __restrict__ ko,
                           unsigned short* __restrict__ vo) {
    __shared__ __align__(16) unsigned short As[2][2][256 * 32];   // 64 KiB
    __shared__ __align__(16) unsigned short Bs[2][2][128 * 32];   // 32 KiB
    const int tid = threadIdx.x;
    const int lane = tid & 63;
    const int wid = tid >> 6;
    const int quad = lane >> 4, l15 = lane & 15;
    const int gm = wid >> 1, gn = wid & 1;
    const int id = blockIdx.x;
    const int rr = id >> 3;
    const int m0 = ((id & 7) * 4 + (rr & 3)) * 256;
    const int n0 = (rr >> 2) * 128;
    const int NT = K >> 6;

    const int lseg = (tid & 3) ^ ((tid >> 3) & 3);
    const int srow = tid >> 2;
    const unsigned short* Ag0 = A + (size_t)(m0 + srow) * lda + lseg * 8;
    const unsigned short* Ag1 = A + (size_t)(m0 + 128 + srow) * lda + lseg * 8;
    const unsigned short* Bg0 = Bt + (size_t)(n0 + srow) * lda + lseg * 8;

    f32x4 acc[4][4] = {};
    short8 af[4], bf[4];

#define STA(bufd, kkd, tt) do { \
    async_cp16(Ag0 + (size_t)(tt) * 64 + (kkd) * 32, &As[bufd][kkd][tid * 8]); \
    async_cp16(Ag1 + (size_t)(tt) * 64 + (kkd) * 32, &As[bufd][kkd][4096 + tid * 8]); } while (0)
#define STB(bufd, kkd, tt) \
    async_cp16(Bg0 + (size_t)(tt) * 64 + (kkd) * 32, &Bs[bufd][kkd][tid * 8])
#define RDA(kkd) do { _Pragma("unroll") for (int mi = 0; mi < 4; mi++) { \
    const int ra = gm * 64 + mi * 16 + l15; \
    af[mi] = *(const short8*)&As[buf][kkd][ra * 32 + ((quad ^ ((ra >> 1) & 3)) << 3)]; } } while (0)
#define RDB(kkd) do { _Pragma("unroll") for (int ni = 0; ni < 4; ni++) { \
    const int rb = gn * 64 + ni * 16 + l15; \
    bf[ni] = *(const short8*)&Bs[buf][kkd][rb * 32 + ((quad ^ ((rb >> 1) & 3)) << 3)]; } } while (0)
#define MM16() do { _Pragma("unroll") for (int mi = 0; mi < 4; mi++) \
    _Pragma("unroll") for (int ni = 0; ni < 4; ni++) \
        acc[mi][ni] = __builtin_amdgcn_mfma_f32_16x16x32_bf16(af[mi], bf[ni], acc[mi][ni], 0, 0, 0); } while (0)

    // prologue: tile0 both kslots (6 loads); ks0 (oldest 3) must land
    STA(0, 0, 0); STB(0, 0, 0);
    STA(0, 1, 0); STB(0, 1, 0);
    VMC(3);
    SCHEDF();
    BARX();

    for (int t = 0; t < NT - 1; t++) {
        const int buf = t & 1;
        const int nb = buf ^ 1;
        // ---- P0: ks0; stage ks0[t+1] ----
        RDA(0); RDB(0);
        STA(nb, 0, t + 1); STB(nb, 0, t + 1);
        BARX();
        __builtin_amdgcn_s_setprio(1);
        MM16();
        __builtin_amdgcn_s_setprio(0);
        VMC(3);     // ks1[t] landed; ks0[t+1] may fly
        SCHEDF();
        BARX();
        // ---- P1: ks1; stage ks1[t+1] ----
        RDA(1); RDB(1);
        STA(nb, 1, t + 1); STB(nb, 1, t + 1);
        BARX();
        __builtin_amdgcn_s_setprio(1);
        MM16();
        __builtin_amdgcn_s_setprio(0);
        VMC(3);     // ks0[t+1] landed; ks1[t+1] may fly
        SCHEDF();
        BARX();
    }
    {   // tail tile
        const int buf = (NT - 1) & 1;
        RDA(0); RDB(0);
        BARX();
        __builtin_amdgcn_s_setprio(1); MM16(); __builtin_amdgcn_s_setprio(0);
        VMC(0);
        SCHEDF();
        BARX();
        RDA(1); RDB(1);
        BARX();
        __builtin_amdgcn_s_setprio(1); MM16(); __builtin_amdgcn_s_setprio(0);
    }
#undef STA
#undef STB
#undef RDA
#undef RDB
#undef MM16

    #pragma unroll
    for (int ni = 0; ni < 4; ni++) {
        const int col = n0 + gn * 64 + ni * 16 + l15;
        const float bv = bias[col];
        #pragma unroll
        for (int mi = 0; mi < 4; mi++) {
            #pragma unroll
            for (int r = 0; r < 4; r++) {
                const int row = m0 + gm * 64 + mi * 16 + quad * 4 + r;
                write_elem<MODE>(row, col, acc[mi][ni][r] + bv, N, outf, outb, resid, qo, ko, vo);
            }
        }
    }
}

// ---------------- causal flash attention, bf16 MFMA ----------------
#define ATT_SC 0.18033688011112042f   // 0.125 * log2(e)
__launch_bounds__(256)
__global__ void attn_kernel(const unsigned short* __restrict__ qb, const unsigned short* __restrict__ kb,
                            const unsigned short* __restrict__ vt, unsigned short* __restrict__ y) {
    __shared__ __align__(16) unsigned short Klds[64 * 64];
    __shared__ __align__(16) unsigned short Vtl[64 * 64];
    __shared__ __align__(16) unsigned short Plds[4][16 * 72];
    const int tid = threadIdx.x;
    const int lane = tid & 63, wid = tid >> 6;
    const int quad = lane >> 4, l15 = lane & 15;
    const int bh = blockIdx.x & 63;
    const int qt = 15 - (int)(blockIdx.x >> 6);
    const size_t baseT = (size_t)bh * Tz;
    const size_t vbase = (size_t)bh * Dz;
    const int qb0 = qt * 128;

    short8 qf[2][2];
    {
        const unsigned short* q0p = qb + (baseT + qb0 + wid * 16 + l15) * Dz + quad * 8;
        qf[0][0] = *(const short8*)q0p;
        qf[0][1] = *(const short8*)(q0p + 32);
        const unsigned short* q1p = q0p + (size_t)64 * Dz;
        qf[1][0] = *(const short8*)q1p;
        qf[1][1] = *(const short8*)(q1p + 32);
    }

    f32x4 o[2][4] = {};
    float lsum[2][4] = {{0.f,0.f,0.f,0.f},{0.f,0.f,0.f,0.f}};

    const int srow = lane >> 3;
    const int swz = ((lane & 7) ^ srow) * 8;
    const unsigned short* kg0 = kb + (baseT + wid * 8 + srow) * Dz + swz;
    const unsigned short* kg1 = kg0 + (size_t)32 * Dz;
    const unsigned short* vg0 = vt + (vbase + wid * 8 + srow) * Tz + swz;
    const unsigned short* vg1 = vg0 + (size_t)32 * Tz;
    unsigned short* kl0 = &Klds[wid * 512 + lane * 8];
    unsigned short* kl1 = kl0 + 2048;
    unsigned short* vl0 = &Vtl[wid * 512 + lane * 8];
    unsigned short* vl1 = vl0 + 2048;

    const int nchunk = 2 * qt + 2;

    for (int ci = 0; ci < nchunk; ci++) {
        const int k0 = ci * 64;
        async_cp16(kg0 + (size_t)k0 * Dz, kl0);
        async_cp16(kg1 + (size_t)k0 * Dz, kl1);
        async_cp16(vg0 + k0, vl0);
        async_cp16(vg1 + k0, vl1);
        __syncthreads();

        #pragma unroll
        for (int t = 0; t < 2; t++) {
            if (t == 0 && ci == nchunk - 1) continue;
            const bool diag = (ci == nchunk - 2 + t);

            f32x4 s[4];
            #pragma unroll
            for (int c = 0; c < 4; c++) {
                const int rk = c * 16 + l15;
                short8 kf0 = *(const short8*)&Klds[rk * 64 + ((quad ^ (rk & 7)) * 8)];
                short8 kf1 = *(const short8*)&Klds[rk * 64 + (((quad + 4) ^ (rk & 7)) * 8)];
                f32x4 z = {};
                z = __builtin_amdgcn_mfma_f32_16x16x32_bf16(qf[t][0], kf0, z, 0, 0, 0);
                s[c] = __builtin_amdgcn_mfma_f32_16x16x32_bf16(qf[t][1], kf1, z, 0, 0, 0);
            }
            const int qr = qb0 + t * 64 + wid * 16 + quad * 4;
            #pragma unroll
            for (int c = 0; c < 4; c++)
                #pragma unroll
                for (int r = 0; r < 4; r++) {
                    float p = exp2f(s[c][r] * ATT_SC);
                    if (diag) {
                        int key = k0 + c * 16 + l15;
                        p = (key <= qr + r) ? p : 0.f;
                    }
                    s[c][r] = p;
                    lsum[t][r] += p;
                }
            unsigned short* P = Plds[wid];
            #pragma unroll
            for (int c = 0; c < 4; c++)
                #pragma unroll
                for (int r = 0; r < 4; r++)
                    P[(quad * 4 + r) * 72 + c * 16 + l15] = f2bf(s[c][r]);
            short8 pf0 = *(const short8*)&P[l15 * 72 + quad * 8];
            short8 pf1 = *(const short8*)&P[l15 * 72 + 32 + quad * 8];
            #pragma unroll
            for (int nc = 0; nc < 4; nc++) {
                const int rv = nc * 16 + l15;
                short8 vf0 = *(const short8*)&Vtl[rv * 64 + ((quad ^ (rv & 7)) * 8)];
                short8 vf1 = *(const short8*)&Vtl[rv * 64 + (((quad + 4) ^ (rv & 7)) * 8)];
                o[t][nc] = __builtin_amdgcn_mfma_f32_16x16x32_bf16(pf0, vf0, o[t][nc], 0, 0, 0);
                o[t][nc] = __builtin_amdgcn_mfma_f32_16x16x32_bf16(pf1, vf1, o[t][nc], 0, 0, 0);
            }
        }
        __syncthreads();
    }

    const int b_ = bh >> 4, hh = bh & 15;
    #pragma unroll
    for (int t = 0; t < 2; t++)
        #pragma unroll
        for (int r = 0; r < 4; r++) {
            float ls = lsum[t][r];
            #pragma unroll
            for (int m = 1; m < 16; m <<= 1) ls += __shfl_xor(ls, m);
            float inv = 1.0f / ls;
            size_t tok = (size_t)qb0 + t * 64 + wid * 16 + quad * 4 + r;
            unsigned short* yr = y + ((size_t)b_ * Tz + tok) * Cz + hh * Dz;
            #pragma unroll
            for (int nc = 0; nc < 4; nc++)
                yr[nc * 16 + l15] = f2bf(o[t][nc][r] * inv);
        }
}

extern "C" void kernel_launch(void* const* d_in, const int* in_sizes, int n_in,
                              void* d_out, int out_size, void* d_ws, size_t ws_size,
                              hipStream_t stream) {
    const float* x    = (const float*)d_in[0];
    const float* ln1g = (const float*)d_in[1];
    const float* ln1b = (const float*)d_in[2];
    const float* Wqkv = (const float*)d_in[3];
    const float* bqkv = (const float*)d_in[4];
    const float* Wo   = (const float*)d_in[5];
    const float* bo   = (const float*)d_in[6];
    const float* ln2g = (const float*)d_in[7];
    const float* ln2b = (const float*)d_in[8];
    const float* Wfc  = (const float*)d_in[9];
    const float* bfc  = (const float*)d_in[10];
    const float* Wpr  = (const float*)d_in[11];
    const float* bpr  = (const float*)d_in[12];
    float* out = (float*)d_out;

    char* ws = (char*)d_ws;
    size_t off = 0;
    auto alloc = [&](size_t bytes) { void* p = ws + off; off += (bytes + 255) & ~(size_t)255; return p; };
    unsigned short* wqkv_t = (unsigned short*)alloc((size_t)3072 * 1024 * 2);
    unsigned short* wo_t   = (unsigned short*)alloc((size_t)1024 * 1024 * 2);
    unsigned short* wfc_t  = (unsigned short*)alloc((size_t)4096 * 1024 * 2);
    unsigned short* wpr_t  = (unsigned short*)alloc((size_t)1024 * 4096 * 2);
    unsigned short* h1     = (unsigned short*)alloc((size_t)MTOK * Cz * 2);
    unsigned short* qbuf   = (unsigned short*)alloc((size_t)MTOK * Cz * 2);
    unsigned short* kbuf   = (unsigned short*)alloc((size_t)MTOK * Cz * 2);
    unsigned short* vbuf   = (unsigned short*)alloc((size_t)MTOK * Cz * 2);   // vt [B,H,D,T]
    unsigned short* ybuf   = (unsigned short*)alloc((size_t)MTOK * Cz * 2);
    float*          x1     = (float*)alloc((size_t)MTOK * Cz * 4);
    unsigned short* h2     = (unsigned short*)alloc((size_t)MTOK * Cz * 2);
    unsigned short* fbuf   = (unsigned short*)alloc((size_t)MTOK * 4096 * 2);
    // vtmp ([B,H,T,D] V before transpose) aliases fbuf: lifetimes disjoint
    unsigned short* vtmp   = fbuf;

    dim3 tb(32, 8);
    transpose_w<<<dim3(3072 / 32, 1024 / 32), tb, 0, stream>>>(Wqkv, wqkv_t, 1024, 3072);
    transpose_w<<<dim3(1024 / 32, 1024 / 32), tb, 0, stream>>>(Wo, wo_t, 1024, 1024);
    transpose_w<<<dim3(4096 / 32, 1024 / 32), tb, 0, stream>>>(Wfc, wfc_t, 1024, 4096);
    transpose_w<<<dim3(1024 / 32, 4096 / 32), tb, 0, stream>>>(Wpr, wpr_t, 4096, 1024);

    ln_kernel<<<MTOK, 256, 0, stream>>>(x, ln1g, ln1b, h1);
    // QKV: M=8192, K=1024, N=3072 -> 384 blocks; V written [B,H,T,D] (coalesced)
    gemm8_n256<MODE_QKV><<<384, 512, 0, stream>>>(h1, wqkv_t, 1024, 1024, 3072, bqkv,
                                                  nullptr, nullptr, nullptr, qbuf, kbuf, vtmp);
    transpose_v<<<dim3(64, 32), 256, 0, stream>>>(vtmp, vbuf);
    attn_kernel<<<1024, 256, 0, stream>>>(qbuf, kbuf, vbuf, ybuf);
    // O-proj: N=1024 -> BN=128, 256 blocks
    gemm8_n128<MODE_RESID><<<256, 512, 0, stream>>>(ybuf, wo_t, 1024, 1024, 1024, bo,
                                                    x1, nullptr, x, nullptr, nullptr, nullptr);
    ln_kernel<<<MTOK, 256, 0, stream>>>(x1, ln2g, ln2b, h2);
    // FC: M=8192, K=1024, N=4096 -> 512 blocks
    gemm8_n256<MODE_GELU><<<512, 512, 0, stream>>>(h2, wfc_t, 1024, 1024, 4096, bfc,
                                                   nullptr, fbuf, nullptr, nullptr, nullptr, nullptr);
    // PR: M=8192, K=4096, N=1024 -> BN=128, 256 blocks
    gemm8_n128<MODE_RESID><<<256, 512, 0, stream>>>(fbuf, wpr_t, 4096, 4096, 1024, bpr,
                                                    out, nullptr, x1, nullptr, nullptr, nullptr);
}

// Round 3
// 514.877 us; speedup vs baseline: 1.0968x; 1.0791x over previous
//
#include <hip/hip_runtime.h>
#include <math.h>

#define Bz 4
#define Tz 2048
#define Cz 1024
#define Hz 16
#define Dz 64
#define MTOK (Bz*Tz)   // 8192

typedef __attribute__((ext_vector_type(8))) short short8;
typedef __attribute__((ext_vector_type(4))) short short4v;
typedef __attribute__((ext_vector_type(4))) float f32x4;

typedef unsigned int u32_g __attribute__((address_space(1)));
typedef unsigned int u32_l __attribute__((address_space(3)));

__device__ __forceinline__ unsigned short f2bf(float f) {
    unsigned int u = __float_as_uint(f);
    u += 0x7fffu + ((u >> 16) & 1u);
    return (unsigned short)(u >> 16);
}
__device__ __forceinline__ float bf2f(unsigned short h) {
    return __uint_as_float((unsigned int)h << 16);
}

__device__ __forceinline__ void async_cp16(const unsigned short* g, unsigned short* l) {
    __builtin_amdgcn_global_load_lds((const u32_g*)g, (u32_l*)l, 16, 0, 0);
}

#define BARX() __builtin_amdgcn_s_barrier()
// counted vmcnt WITH memory clobber: compiler must not hoist the slot-t ds_reads
// above the wait that guarantees slot-t staging landed.
#define VMCM(n) asm volatile("s_waitcnt vmcnt(" #n ")" ::: "memory")

// ---------------- weight transpose: W[K][N] f32 -> Wt[N][K] bf16 ----------------
__global__ void transpose_w(const float* __restrict__ W, unsigned short* __restrict__ Wt,
                            int K, int N) {
    __shared__ float tile[32][33];
    int n0 = blockIdx.x * 32, k0 = blockIdx.y * 32;
    int tx = threadIdx.x, ty = threadIdx.y;   // (32, 8)
    #pragma unroll
    for (int i = 0; i < 4; i++)
        tile[ty + i * 8][tx] = W[(size_t)(k0 + ty + i * 8) * N + n0 + tx];
    __syncthreads();
    #pragma unroll
    for (int i = 0; i < 4; i++)
        Wt[(size_t)(n0 + ty + i * 8) * K + k0 + tx] = f2bf(tile[tx][ty + i * 8]);
}

// ---------------- V transpose: vtmp[B*H][T][D] -> vt[B*H][D][T] -----------------
__global__ void transpose_v(const unsigned short* __restrict__ in, unsigned short* __restrict__ out) {
    __shared__ unsigned short tile[64][68];
    const int bh = blockIdx.x;        // 0..63
    const int t0 = blockIdx.y * 64;   // 32 tiles along T
    const int tid = threadIdx.x;      // 256
    const int r4 = tid >> 4;          // 0..15
    const int c4 = tid & 15;          // 0..15
    #pragma unroll
    for (int p = 0; p < 4; p++) {
        const int r = p * 16 + r4;
        *(short4v*)&tile[r][c4 * 4] =
            *(const short4v*)&in[((size_t)bh * Tz + t0 + r) * Dz + c4 * 4];
    }
    __syncthreads();
    #pragma unroll
    for (int p = 0; p < 4; p++) {
        const int d = p * 16 + r4;
        short4v o;
        #pragma unroll
        for (int j = 0; j < 4; j++) o[j] = tile[c4 * 4 + j][d];
        *(short4v*)&out[((size_t)bh * Dz + d) * Tz + t0 + c4 * 4] = o;
    }
}

// ---------------- layernorm: fp32 in -> bf16 out ----------------
__global__ void ln_kernel(const float* __restrict__ x, const float* __restrict__ g,
                          const float* __restrict__ bb, unsigned short* __restrict__ out) {
    int tok = blockIdx.x, tid = threadIdx.x;
    const float4 v = ((const float4*)(x + (size_t)tok * Cz))[tid];
    float s = v.x + v.y + v.z + v.w;
    float sq = v.x * v.x + v.y * v.y + v.z * v.z + v.w * v.w;
    #pragma unroll
    for (int m = 1; m < 64; m <<= 1) { s += __shfl_xor(s, m); sq += __shfl_xor(sq, m); }
    __shared__ float red[8];
    int lane = tid & 63, wid = tid >> 6;
    if (!lane) { red[wid] = s; red[4 + wid] = sq; }
    __syncthreads();
    s = red[0] + red[1] + red[2] + red[3];
    sq = red[4] + red[5] + red[6] + red[7];
    float mu = s * (1.0f / Cz);
    float var = sq * (1.0f / Cz) - mu * mu;
    float rs = rsqrtf(var + 1e-5f);
    float4 gv = ((const float4*)g)[tid];
    float4 bv = ((const float4*)bb)[tid];
    short4v o;
    o[0] = f2bf((v.x - mu) * rs * gv.x + bv.x);
    o[1] = f2bf((v.y - mu) * rs * gv.y + bv.y);
    o[2] = f2bf((v.z - mu) * rs * gv.z + bv.z);
    o[3] = f2bf((v.w - mu) * rs * gv.w + bv.w);
    *(short4v*)(out + (size_t)tok * Cz + tid * 4) = o;
}

#define MODE_QKV 0
#define MODE_RESID 1
#define MODE_GELU 2

template <int MODE>
__device__ __forceinline__ void write_elem(int row, int col, float val, int N,
                                           float* __restrict__ outf, unsigned short* __restrict__ outb,
                                           const float* __restrict__ resid,
                                           unsigned short* __restrict__ qo, unsigned short* __restrict__ ko,
                                           unsigned short* __restrict__ vo) {
    if constexpr (MODE == MODE_QKV) {
        int which = col >> 10, cc = col & 1023;
        int hh = cc >> 6, dd = cc & 63;
        int b_ = row >> 11, t = row & 2047;
        unsigned short* dst = (which == 0) ? qo : (which == 1) ? ko : vo;
        dst[((size_t)(b_ * Hz + hh) * Tz + t) * Dz + dd] = f2bf(val);
    } else if constexpr (MODE == MODE_RESID) {
        size_t idx = (size_t)row * N + col;
        outf[idx] = val + resid[idx];
    } else {  // MODE_GELU, tanh-form
        float c = val * (1.0f + 0.044715f * val * val);
        float e = __expf(1.5957691216057308f * c);
        outb[(size_t)row * N + col] = f2bf(val * e / (1.0f + e));
    }
}

// ================= flat-body triple-buffer GEMM, BM=256 x BN=256, BK=32 =========
// 512 thr = 8 waves (2M x 4N), wave tile 128x64. LDS: 3 slots x [A 256x32|B 256x32]
// = 96 KiB. One barrier + one counted vmcnt per K-tile; stage of tile t+2 issues
// right after the barrier; 12 ds_read_b128 + 32 MFMA form ONE scheduling region so
// the compiler interleaves them with partial lgkmcnt (m97-style). vmcnt never 0
// in the loop (2-tile prefetch depth); slot rotation 3 apart is WAR-safe because
// tile t-1's reads are consumed by its MFMAs before the tile-t barrier.
template <int MODE>
__launch_bounds__(512, 1)
__global__ void gemm3_n256(const unsigned short* __restrict__ A, const unsigned short* __restrict__ Bt,
                           int lda, int K, int N, const float* __restrict__ bias,
                           float* __restrict__ outf, unsigned short* __restrict__ outb,
                           const float* __restrict__ resid,
                           unsigned short* __restrict__ qo, unsigned short* __restrict__ ko,
                           unsigned short* __restrict__ vo) {
    __shared__ __align__(16) unsigned short LDS[3 * 16384];
    const int tid = threadIdx.x;
    const int lane = tid & 63;
    const int wid = tid >> 6;
    const int quad = lane >> 4, l15 = lane & 15;
    const int gm = wid >> 2, gn = wid & 3;
    const int id = blockIdx.x;
    const int rr = id >> 3;
    const int m0 = ((id & 7) * 4 + (rr & 3)) * 256;   // XCD-contiguous m-tiles
    const int n0 = (rr >> 2) * 256;
    const int NT = K >> 5;

    // staging: thread -> row tid/4 (and +128), phys 16B-seg tid&3; global col
    // pre-swizzled (seg ^ (row>>1)&3) so LDS dest stays linear.
    const int lseg = (tid & 3) ^ ((tid >> 3) & 3);
    const int srow = tid >> 2;
    const unsigned short* Ag0 = A + (size_t)(m0 + srow) * lda + lseg * 8;
    const unsigned short* Ag1 = A + (size_t)(m0 + 128 + srow) * lda + lseg * 8;
    const unsigned short* Bg0 = Bt + (size_t)(n0 + srow) * lda + lseg * 8;
    const unsigned short* Bg1 = Bt + (size_t)(n0 + 128 + srow) * lda + lseg * 8;

    unsigned short* sl0 = LDS;
    unsigned short* sl1 = LDS + 16384;
    unsigned short* sl2 = LDS + 32768;

    int offA[8], offB[4];
    #pragma unroll
    for (int mi = 0; mi < 8; mi++) {
        const int ra = gm * 128 + mi * 16 + l15;
        offA[mi] = ra * 32 + ((quad ^ ((ra >> 1) & 3)) << 3);
    }
    #pragma unroll
    for (int ni = 0; ni < 4; ni++) {
        const int rb = gn * 64 + ni * 16 + l15;
        offB[ni] = 8192 + rb * 32 + ((quad ^ ((rb >> 1) & 3)) << 3);
    }

    f32x4 acc[8][4] = {};

#define STAGE(sp, tt) do { \
    const size_t kof = (size_t)(tt) * 32; \
    async_cp16(Ag0 + kof, (sp) + tid * 8); \
    async_cp16(Ag1 + kof, (sp) + 4096 + tid * 8); \
    async_cp16(Bg0 + kof, (sp) + 8192 + tid * 8); \
    async_cp16(Bg1 + kof, (sp) + 12288 + tid * 8); } while (0)
#define COMPUTE(sp) do { \
    short8 af[8], bf[4]; \
    _Pragma("unroll") for (int mi = 0; mi < 8; mi++) af[mi] = *(const short8*)((sp) + offA[mi]); \
    _Pragma("unroll") for (int ni = 0; ni < 4; ni++) bf[ni] = *(const short8*)((sp) + offB[ni]); \
    __builtin_amdgcn_s_setprio(1); \
    _Pragma("unroll") for (int mi = 0; mi < 8; mi++) \
        _Pragma("unroll") for (int ni = 0; ni < 4; ni++) \
            acc[mi][ni] = __builtin_amdgcn_mfma_f32_16x16x32_bf16(af[mi], bf[ni], acc[mi][ni], 0, 0, 0); \
    __builtin_amdgcn_s_setprio(0); } while (0)

    STAGE(sl0, 0);
    STAGE(sl1, 1);

    for (int t = 0; t < NT - 1; t++) {
        VMCM(4);                     // tile t landed; tile t+1 may fly
        BARX();
        if (t + 2 < NT) STAGE(sl2, t + 2);
        COMPUTE(sl0);
        unsigned short* tmp = sl0; sl0 = sl1; sl1 = sl2; sl2 = tmp;
    }
    VMCM(0);                         // last tile (once per kernel)
    BARX();
    COMPUTE(sl0);
#undef STAGE
#undef COMPUTE

    #pragma unroll
    for (int ni = 0; ni < 4; ni++) {
        const int col = n0 + gn * 64 + ni * 16 + l15;
        const float bv = bias[col];
        #pragma unroll
        for (int mi = 0; mi < 8; mi++) {
            #pragma unroll
            for (int r = 0; r < 4; r++) {
                const int row = m0 + gm * 128 + mi * 16 + quad * 4 + r;
                write_elem<MODE>(row, col, acc[mi][ni][r] + bv, N, outf, outb, resid, qo, ko, vo);
            }
        }
    }
}

// ================= flat-body triple-buffer GEMM, BM=256 x BN=128, BK=32 =========
// 512 thr = 8 waves (4M x 2N), wave tile 64x64. LDS: 3 x [A 256x32|B 128x32] = 72 KiB.
template <int MODE>
__launch_bounds__(512, 1)
__global__ void gemm3_n128(const unsigned short* __restrict__ A, const unsigned short* __restrict__ Bt,
                           int lda, int K, int N, const float* __restrict__ bias,
                           float* __restrict__ outf, unsigned short* __restrict__ outb,
                           const float* __restrict__ resid,
                           unsigned short* __restrict__ qo, unsigned short* __restrict__ ko,
                           unsigned short* __restrict__ vo) {
    __shared__ __align__(16) unsigned short LDS[3 * 12288];
    const int tid = threadIdx.x;
    const int lane = tid & 63;
    const int wid = tid >> 6;
    const int quad = lane >> 4, l15 = lane & 15;
    const int gm = wid >> 1, gn = wid & 1;
    const int id = blockIdx.x;
    const int rr = id >> 3;
    const int m0 = ((id & 7) * 4 + (rr & 3)) * 256;
    const int n0 = (rr >> 2) * 128;
    const int NT = K >> 5;

    const int lseg = (tid & 3) ^ ((tid >> 3) & 3);
    const int srow = tid >> 2;
    const unsigned short* Ag0 = A + (size_t)(m0 + srow) * lda + lseg * 8;
    const unsigned short* Ag1 = A + (size_t)(m0 + 128 + srow) * lda + lseg * 8;
    const unsigned short* Bg0 = Bt + (size_t)(n0 + srow) * lda + lseg * 8;

    unsigned short* sl0 = LDS;
    unsigned short* sl1 = LDS + 12288;
    unsigned short* sl2 = LDS + 24576;

    int offA[4], offB[4];
    #pragma unroll
    for (int mi = 0; mi < 4; mi++) {
        const int ra = gm * 64 + mi * 16 + l15;
        offA[mi] = ra * 32 + ((quad ^ ((ra >> 1) & 3)) << 3);
    }
    #pragma unroll
    for (int ni = 0; ni < 4; ni++) {
        const int rb = gn * 64 + ni * 16 + l15;
        offB[ni] = 8192 + rb * 32 + ((quad ^ ((rb >> 1) & 3)) << 3);
    }

    f32x4 acc[4][4] = {};

#define STAGE(sp, tt) do { \
    const size_t kof = (size_t)(tt) * 32; \
    async_cp16(Ag0 + kof, (sp) + tid * 8); \
    async_cp16(Ag1 + kof, (sp) + 4096 + tid * 8); \
    async_cp16(Bg0 + kof, (sp) + 8192 + tid * 8); } while (0)
#define COMPUTE(sp) do { \
    short8 af[4], bf[4]; \
    _Pragma("unroll") for (int mi = 0; mi < 4; mi++) af[mi] = *(const short8*)((sp) + offA[mi]); \
    _Pragma("unroll") for (int ni = 0; ni < 4; ni++) bf[ni] = *(const short8*)((sp) + offB[ni]); \
    __builtin_amdgcn_s_setprio(1); \
    _Pragma("unroll") for (int mi = 0; mi < 4; mi++) \
        _Pragma("unroll") for (int ni = 0; ni < 4; ni++) \
            acc[mi][ni] = __builtin_amdgcn_mfma_f32_16x16x32_bf16(af[mi], bf[ni], acc[mi][ni], 0, 0, 0); \
    __builtin_amdgcn_s_setprio(0); } while (0)

    STAGE(sl0, 0);
    STAGE(sl1, 1);

    for (int t = 0; t < NT - 1; t++) {
        VMCM(3);
        BARX();
        if (t + 2 < NT) STAGE(sl2, t + 2);
        COMPUTE(sl0);
        unsigned short* tmp = sl0; sl0 = sl1; sl1 = sl2; sl2 = tmp;
    }
    VMCM(0);
    BARX();
    COMPUTE(sl0);
#undef STAGE
#undef COMPUTE

    #pragma unroll
    for (int ni = 0; ni < 4; ni++) {
        const int col = n0 + gn * 64 + ni * 16 + l15;
        const float bv = bias[col];
        #pragma unroll
        for (int mi = 0; mi < 4; mi++) {
            #pragma unroll
            for (int r = 0; r < 4; r++) {
                const int row = m0 + gm * 64 + mi * 16 + quad * 4 + r;
                write_elem<MODE>(row, col, acc[mi][ni][r] + bv, N, outf, outb, resid, qo, ko, vo);
            }
        }
    }
}

// ---------------- causal flash attention, bf16 MFMA ----------------
#define ATT_SC 0.18033688011112042f   // 0.125 * log2(e)
__launch_bounds__(256)
__global__ void attn_kernel(const unsigned short* __restrict__ qb, const unsigned short* __restrict__ kb,
                            const unsigned short* __restrict__ vt, unsigned short* __restrict__ y) {
    __shared__ __align__(16) unsigned short Klds[64 * 64];
    __shared__ __align__(16) unsigned short Vtl[64 * 64];
    __shared__ __align__(16) unsigned short Plds[4][16 * 72];
    const int tid = threadIdx.x;
    const int lane = tid & 63, wid = tid >> 6;
    const int quad = lane >> 4, l15 = lane & 15;
    const int bh = blockIdx.x & 63;
    const int qt = 15 - (int)(blockIdx.x >> 6);
    const size_t baseT = (size_t)bh * Tz;
    const size_t vbase = (size_t)bh * Dz;
    const int qb0 = qt * 128;

    short8 qf[2][2];
    {
        const unsigned short* q0p = qb + (baseT + qb0 + wid * 16 + l15) * Dz + quad * 8;
        qf[0][0] = *(const short8*)q0p;
        qf[0][1] = *(const short8*)(q0p + 32);
        const unsigned short* q1p = q0p + (size_t)64 * Dz;
        qf[1][0] = *(const short8*)q1p;
        qf[1][1] = *(const short8*)(q1p + 32);
    }

    f32x4 o[2][4] = {};
    float lsum[2][4] = {{0.f,0.f,0.f,0.f},{0.f,0.f,0.f,0.f}};

    const int srow = lane >> 3;
    const int swz = ((lane & 7) ^ srow) * 8;
    const unsigned short* kg0 = kb + (baseT + wid * 8 + srow) * Dz + swz;
    const unsigned short* kg1 = kg0 + (size_t)32 * Dz;
    const unsigned short* vg0 = vt + (vbase + wid * 8 + srow) * Tz + swz;
    const unsigned short* vg1 = vg0 + (size_t)32 * Tz;
    unsigned short* kl0 = &Klds[wid * 512 + lane * 8];
    unsigned short* kl1 = kl0 + 2048;
    unsigned short* vl0 = &Vtl[wid * 512 + lane * 8];
    unsigned short* vl1 = vl0 + 2048;

    const int nchunk = 2 * qt + 2;

    for (int ci = 0; ci < nchunk; ci++) {
        const int k0 = ci * 64;
        async_cp16(kg0 + (size_t)k0 * Dz, kl0);
        async_cp16(kg1 + (size_t)k0 * Dz, kl1);
        async_cp16(vg0 + k0, vl0);
        async_cp16(vg1 + k0, vl1);
        __syncthreads();

        #pragma unroll
        for (int t = 0; t < 2; t++) {
            if (t == 0 && ci == nchunk - 1) continue;
            const bool diag = (ci == nchunk - 2 + t);

            f32x4 s[4];
            #pragma unroll
            for (int c = 0; c < 4; c++) {
                const int rk = c * 16 + l15;
                short8 kf0 = *(const short8*)&Klds[rk * 64 + ((quad ^ (rk & 7)) * 8)];
                short8 kf1 = *(const short8*)&Klds[rk * 64 + (((quad + 4) ^ (rk & 7)) * 8)];
                f32x4 z = {};
                z = __builtin_amdgcn_mfma_f32_16x16x32_bf16(qf[t][0], kf0, z, 0, 0, 0);
                s[c] = __builtin_amdgcn_mfma_f32_16x16x32_bf16(qf[t][1], kf1, z, 0, 0, 0);
            }
            const int qr = qb0 + t * 64 + wid * 16 + quad * 4;
            #pragma unroll
            for (int c = 0; c < 4; c++)
                #pragma unroll
                for (int r = 0; r < 4; r++) {
                    float p = exp2f(s[c][r] * ATT_SC);
                    if (diag) {
                        int key = k0 + c * 16 + l15;
                        p = (key <= qr + r) ? p : 0.f;
                    }
                    s[c][r] = p;
                    lsum[t][r] += p;
                }
            unsigned short* P = Plds[wid];
            #pragma unroll
            for (int c = 0; c < 4; c++)
                #pragma unroll
                for (int r = 0; r < 4; r++)
                    P[(quad * 4 + r) * 72 + c * 16 + l15] = f2bf(s[c][r]);
            short8 pf0 = *(const short8*)&P[l15 * 72 + quad * 8];
            short8 pf1 = *(const short8*)&P[l15 * 72 + 32 + quad * 8];
            #pragma unroll
            for (int nc = 0; nc < 4; nc++) {
                const int rv = nc * 16 + l15;
                short8 vf0 = *(const short8*)&Vtl[rv * 64 + ((quad ^ (rv & 7)) * 8)];
                short8 vf1 = *(const short8*)&Vtl[rv * 64 + (((quad + 4) ^ (rv & 7)) * 8)];
                o[t][nc] = __builtin_amdgcn_mfma_f32_16x16x32_bf16(pf0, vf0, o[t][nc], 0, 0, 0);
                o[t][nc] = __builtin_amdgcn_mfma_f32_16x16x32_bf16(pf1, vf1, o[t][nc], 0, 0, 0);
            }
        }
        __syncthreads();
    }

    const int b_ = bh >> 4, hh = bh & 15;
    #pragma unroll
    for (int t = 0; t < 2; t++)
        #pragma unroll
        for (int r = 0; r < 4; r++) {
            float ls = lsum[t][r];
            #pragma unroll
            for (int m = 1; m < 16; m <<= 1) ls += __shfl_xor(ls, m);
            float inv = 1.0f / ls;
            size_t tok = (size_t)qb0 + t * 64 + wid * 16 + quad * 4 + r;
            unsigned short* yr = y + ((size_t)b_ * Tz + tok) * Cz + hh * Dz;
            #pragma unroll
            for (int nc = 0; nc < 4; nc++)
                yr[nc * 16 + l15] = f2bf(o[t][nc][r] * inv);
        }
}

extern "C" void kernel_launch(void* const* d_in, const int* in_sizes, int n_in,
                              void* d_out, int out_size, void* d_ws, size_t ws_size,
                              hipStream_t stream) {
    const float* x    = (const float*)d_in[0];
    const float* ln1g = (const float*)d_in[1];
    const float* ln1b = (const float*)d_in[2];
    const float* Wqkv = (const float*)d_in[3];
    const float* bqkv = (const float*)d_in[4];
    const float* Wo   = (const float*)d_in[5];
    const float* bo   = (const float*)d_in[6];
    const float* ln2g = (const float*)d_in[7];
    const float* ln2b = (const float*)d_in[8];
    const float* Wfc  = (const float*)d_in[9];
    const float* bfc  = (const float*)d_in[10];
    const float* Wpr  = (const float*)d_in[11];
    const float* bpr  = (const float*)d_in[12];
    float* out = (float*)d_out;

    char* ws = (char*)d_ws;
    size_t off = 0;
    auto alloc = [&](size_t bytes) { void* p = ws + off; off += (bytes + 255) & ~(size_t)255; return p; };
    unsigned short* wqkv_t = (unsigned short*)alloc((size_t)3072 * 1024 * 2);
    unsigned short* wo_t   = (unsigned short*)alloc((size_t)1024 * 1024 * 2);
    unsigned short* wfc_t  = (unsigned short*)alloc((size_t)4096 * 1024 * 2);
    unsigned short* wpr_t  = (unsigned short*)alloc((size_t)1024 * 4096 * 2);
    unsigned short* h1     = (unsigned short*)alloc((size_t)MTOK * Cz * 2);
    unsigned short* qbuf   = (unsigned short*)alloc((size_t)MTOK * Cz * 2);
    unsigned short* kbuf   = (unsigned short*)alloc((size_t)MTOK * Cz * 2);
    unsigned short* vbuf   = (unsigned short*)alloc((size_t)MTOK * Cz * 2);   // vt [B,H,D,T]
    unsigned short* ybuf   = (unsigned short*)alloc((size_t)MTOK * Cz * 2);
    float*          x1     = (float*)alloc((size_t)MTOK * Cz * 4);
    unsigned short* h2     = (unsigned short*)alloc((size_t)MTOK * Cz * 2);
    unsigned short* fbuf   = (unsigned short*)alloc((size_t)MTOK * 4096 * 2);
    // vtmp ([B,H,T,D] V before transpose) aliases fbuf: lifetimes disjoint
    unsigned short* vtmp   = fbuf;

    dim3 tb(32, 8);
    transpose_w<<<dim3(3072 / 32, 1024 / 32), tb, 0, stream>>>(Wqkv, wqkv_t, 1024, 3072);
    transpose_w<<<dim3(1024 / 32, 1024 / 32), tb, 0, stream>>>(Wo, wo_t, 1024, 1024);
    transpose_w<<<dim3(4096 / 32, 1024 / 32), tb, 0, stream>>>(Wfc, wfc_t, 1024, 4096);
    transpose_w<<<dim3(1024 / 32, 4096 / 32), tb, 0, stream>>>(Wpr, wpr_t, 4096, 1024);

    ln_kernel<<<MTOK, 256, 0, stream>>>(x, ln1g, ln1b, h1);
    // QKV: M=8192, K=1024, N=3072 -> BN=128: 32m x 24n = 768 blocks (3 clean rounds)
    gemm3_n128<MODE_QKV><<<768, 512, 0, stream>>>(h1, wqkv_t, 1024, 1024, 3072, bqkv,
                                                  nullptr, nullptr, nullptr, qbuf, kbuf, vtmp);
    transpose_v<<<dim3(64, 32), 256, 0, stream>>>(vtmp, vbuf);
    attn_kernel<<<1024, 256, 0, stream>>>(qbuf, kbuf, vbuf, ybuf);
    // O-proj: N=1024 -> 256 blocks
    gemm3_n128<MODE_RESID><<<256, 512, 0, stream>>>(ybuf, wo_t, 1024, 1024, 1024, bo,
                                                    x1, nullptr, x, nullptr, nullptr, nullptr);
    ln_kernel<<<MTOK, 256, 0, stream>>>(x1, ln2g, ln2b, h2);
    // FC: M=8192, K=1024, N=4096 -> BN=256: 32m x 16n = 512 blocks (2 clean rounds)
    gemm3_n256<MODE_GELU><<<512, 512, 0, stream>>>(h2, wfc_t, 1024, 1024, 4096, bfc,
                                                   nullptr, fbuf, nullptr, nullptr, nullptr, nullptr);
    // PR: M=8192, K=4096, N=1024 -> 256 blocks
    gemm3_n128<MODE_RESID><<<256, 512, 0, stream>>>(fbuf, wpr_t, 4096, 4096, 1024, bpr,
                                                    out, nullptr, x1, nullptr, nullptr, nullptr);
}